// Round 1
// baseline (51.685 us; speedup 1.0000x reference)
//
#include <hip/hip_runtime.h>
#include <hip/hip_bf16.h>
#include <math.h>

// ABMIL gated-attention pooling, single-pass flash-style softmax.
// B=4 bags, N=16384 instances, D=1024 features, L=4 outputs. All f32.

#define NB 4
#define NN 16384
#define DD 1024
#define LL 4

struct Partial {
    float z[DD];   // unnormalized weighted sum, scaled by exp(-m)
    float m;       // running max of scores
    float s;       // running sum of exp(a - m)
    float pad[6];  // -> 1032 floats = 4128 bytes (16B multiple)
};

// ---------------------------------------------------------------------------
// Mode detect: is `valid` stored as bytes (numpy bool), int32, or float32?
// Deterministic classification from the first 4096 bytes (always in-bounds:
// byte layout has 65536 bytes). mode: 0=byte, 1=int32, 2=float32.
// ---------------------------------------------------------------------------
__global__ __launch_bounds__(256) void detect_mode_kernel(
    const unsigned int* __restrict__ v, int* __restrict__ mode_out) {
    __shared__ int not_i, not_f;
    if (threadIdx.x == 0) { not_i = 0; not_f = 0; }
    __syncthreads();
    int bi = 0, bf = 0;
    #pragma unroll
    for (int j = 0; j < 4; ++j) {
        unsigned int x = v[threadIdx.x * 4 + j];
        if (x != 0u && x != 1u) bi = 1;
        if (x != 0u && x != 0x3F800000u) bf = 1;  // 1.0f
    }
    if (bi) atomicOr(&not_i, 1);
    if (bf) atomicOr(&not_f, 1);
    __syncthreads();
    if (threadIdx.x == 0) *mode_out = (!not_i) ? 1 : ((!not_f) ? 2 : 0);
}

// ---------------------------------------------------------------------------
// Main kernel: grid (nblk, NB), 256 threads (4 waves). Each wave processes
// rows_per_block/4 consecutive rows; per valid row: load 1024 f32 into regs
// (16/lane), two dots via wave shuffle-reduce, gated score, online-softmax
// accumulate into 16 regs/lane. Invalid rows are skipped entirely (their
// exp(-10000 - M) underflows to exactly 0 in f32, matching the reference).
// Then LDS-combine 4 waves -> one Partial per block.
// ---------------------------------------------------------------------------
__global__ __launch_bounds__(256) void abmil_partial_kernel(
    const float* __restrict__ xs, const void* __restrict__ valid,
    const float* __restrict__ w1, const float* __restrict__ w2,
    Partial* __restrict__ parts, const int* __restrict__ mode_p,
    int nblk, int rows_per_block) {
    const int blk  = blockIdx.x;
    const int bag  = blockIdx.y;
    const int tid  = threadIdx.x;
    const int wave = tid >> 6;
    const int lane = tid & 63;
    const int mode = *mode_p;

    // preload gate weights into registers (16 f32/lane each)
    const float4* w1v = (const float4*)w1;
    const float4* w2v = (const float4*)w2;
    float4 w1r[4], w2r[4];
    #pragma unroll
    for (int k = 0; k < 4; ++k) {
        w1r[k] = w1v[k * 64 + lane];
        w2r[k] = w2v[k * 64 + lane];
    }

    const int rows_per_wave = rows_per_block >> 2;
    const int n0 = blk * rows_per_block + wave * rows_per_wave;

    const unsigned char* vb = (const unsigned char*)valid;
    const int*           vi = (const int*)valid;
    const float*         vf = (const float*)valid;
    const size_t vbase = (size_t)bag * NN;

    float m = -INFINITY, s = 0.0f;
    float4 z[4];
    #pragma unroll
    for (int k = 0; k < 4; ++k) z[k] = make_float4(0.f, 0.f, 0.f, 0.f);

    for (int i = 0; i < rows_per_wave; ++i) {
        const int n = n0 + i;
        bool v;
        if (mode == 1)      v = (vi[vbase + n] != 0);
        else if (mode == 2) v = (vf[vbase + n] != 0.0f);
        else                v = (vb[vbase + n] != 0);
        if (!v) continue;

        const float4* xp = (const float4*)(xs + ((size_t)bag * NN + n) * DD);
        float4 xv[4];
        #pragma unroll
        for (int k = 0; k < 4; ++k) xv[k] = xp[k * 64 + lane];

        float d1 = 0.f, d2 = 0.f;
        #pragma unroll
        for (int k = 0; k < 4; ++k) {
            d1 += xv[k].x * w1r[k].x + xv[k].y * w1r[k].y +
                  xv[k].z * w1r[k].z + xv[k].w * w1r[k].w;
            d2 += xv[k].x * w2r[k].x + xv[k].y * w2r[k].y +
                  xv[k].z * w2r[k].z + xv[k].w * w2r[k].w;
        }
        #pragma unroll
        for (int off = 32; off > 0; off >>= 1) {
            d1 += __shfl_xor(d1, off, 64);
            d2 += __shfl_xor(d2, off, 64);
        }
        const float a = tanhf(d1) * (1.0f / (1.0f + __expf(-d2)));

        if (a > m) {
            const float sc = (m > -1e37f) ? __expf(m - a) : 0.0f;
            s *= sc;
            #pragma unroll
            for (int k = 0; k < 4; ++k) {
                z[k].x *= sc; z[k].y *= sc; z[k].z *= sc; z[k].w *= sc;
            }
            m = a;
        }
        const float p = __expf(a - m);
        s += p;
        #pragma unroll
        for (int k = 0; k < 4; ++k) {
            z[k].x += p * xv[k].x; z[k].y += p * xv[k].y;
            z[k].z += p * xv[k].z; z[k].w += p * xv[k].w;
        }
    }

    // combine 4 waves via LDS
    __shared__ float zsh[4][DD];
    __shared__ float msh[4], ssh[4];
    #pragma unroll
    for (int k = 0; k < 4; ++k) ((float4*)zsh[wave])[k * 64 + lane] = z[k];
    if (lane == 0) { msh[wave] = m; ssh[wave] = s; }
    __syncthreads();

    const float M = fmaxf(fmaxf(msh[0], msh[1]), fmaxf(msh[2], msh[3]));
    float scw[4];
    #pragma unroll
    for (int w = 0; w < 4; ++w)
        scw[w] = (msh[w] > -1e37f) ? __expf(msh[w] - M) : 0.0f;

    Partial* po = &parts[(size_t)bag * nblk + blk];
    float4 acc = make_float4(0.f, 0.f, 0.f, 0.f);
    #pragma unroll
    for (int w = 0; w < 4; ++w) {
        const float4 zv = ((const float4*)zsh[w])[tid];
        acc.x += scw[w] * zv.x; acc.y += scw[w] * zv.y;
        acc.z += scw[w] * zv.z; acc.w += scw[w] * zv.w;
    }
    ((float4*)po->z)[tid] = acc;
    if (tid == 0) {
        po->m = M;
        po->s = scw[0] * ssh[0] + scw[1] * ssh[1] +
                scw[2] * ssh[2] + scw[3] * ssh[3];
    }
}

// ---------------------------------------------------------------------------
// Group-combine: reduce `group` input Partials -> 1 output Partial per block.
// grid (nout_per_bag, NB), 256 threads (each owns one float4 of z).
// ---------------------------------------------------------------------------
__global__ __launch_bounds__(256) void combine_kernel(
    const Partial* __restrict__ pin, Partial* __restrict__ pout,
    int nin_per_bag, int group, int nout_per_bag) {
    const int g   = blockIdx.x;
    const int bag = blockIdx.y;
    const int tid = threadIdx.x;
    const int i0  = g * group;
    int cnt = nin_per_bag - i0;
    if (cnt > group) cnt = group;
    if (cnt < 0) cnt = 0;
    const Partial* base = pin + (size_t)bag * nin_per_bag + i0;

    float M = -INFINITY;
    for (int j = 0; j < cnt; ++j) M = fmaxf(M, base[j].m);

    float4 acc = make_float4(0.f, 0.f, 0.f, 0.f);
    float sacc = 0.0f;
    for (int j = 0; j < cnt; ++j) {
        const float mj = base[j].m;
        const float sc = (mj > -1e37f && M > -1e37f) ? __expf(mj - M) : 0.0f;
        const float4 zv = ((const float4*)base[j].z)[tid];
        acc.x += sc * zv.x; acc.y += sc * zv.y;
        acc.z += sc * zv.z; acc.w += sc * zv.w;
        sacc += sc * base[j].s;
    }
    Partial* po = pout + (size_t)bag * nout_per_bag + g;
    ((float4*)po->z)[tid] = acc;
    if (tid == 0) { po->m = M; po->s = sacc; }
}

// ---------------------------------------------------------------------------
// Finalize: grid NB, 1024 threads. Global combine of nin Partials, normalize,
// then out[b,l] = sum_d z[d] * wf[l,d] via per-wave shuffle reduce.
// ---------------------------------------------------------------------------
__global__ __launch_bounds__(1024) void finalize_kernel(
    const Partial* __restrict__ pin, int nin_per_bag,
    const float* __restrict__ wf, float* __restrict__ out) {
    const int bag  = blockIdx.x;
    const int tid  = threadIdx.x;   // == feature dim d
    const int lane = tid & 63;
    const int wave = tid >> 6;
    const Partial* base = pin + (size_t)bag * nin_per_bag;

    float M = -INFINITY;
    for (int j = 0; j < nin_per_bag; ++j) M = fmaxf(M, base[j].m);

    float s_tot = 0.0f, acc = 0.0f;
    for (int j = 0; j < nin_per_bag; ++j) {
        const float mj = base[j].m;
        const float sc = (mj > -1e37f) ? __expf(mj - M) : 0.0f;
        s_tot += sc * base[j].s;
        acc   += sc * base[j].z[tid];
    }
    const float zn = acc / s_tot;

    __shared__ float zsh[DD];
    zsh[tid] = zn;
    __syncthreads();

    if (wave < LL) {
        float p = 0.0f;
        #pragma unroll
        for (int k = 0; k < 16; ++k) {
            const int d = lane + k * 64;
            p += zsh[d] * wf[wave * DD + d];
        }
        #pragma unroll
        for (int off = 32; off > 0; off >>= 1) p += __shfl_xor(p, off, 64);
        if (lane == 0) out[bag * LL + wave] = p;
    }
}

// ---------------------------------------------------------------------------
extern "C" void kernel_launch(void* const* d_in, const int* in_sizes, int n_in,
                              void* d_out, int out_size, void* d_ws, size_t ws_size,
                              hipStream_t stream) {
    const float* xs    = (const float*)d_in[0];
    const void*  valid = d_in[1];
    const float* w1    = (const float*)d_in[2];
    const float* w2    = (const float*)d_in[3];
    const float* wf    = (const float*)d_in[4];
    float* out = (float*)d_out;

    int* mode_p = (int*)d_ws;
    char* pbase = (char*)d_ws + 256;

    // pick nblk (blocks per bag) to fit workspace: level0 (nblk) + level1 (16)
    int nblk = 256;
    while (nblk > 4) {
        size_t need = 256 + (size_t)NB * ((size_t)nblk + 16) * sizeof(Partial);
        if (need <= ws_size) break;
        nblk >>= 1;
    }
    const int rows_per_block = NN / nblk;
    Partial* p0 = (Partial*)pbase;
    Partial* p1 = p0 + (size_t)NB * nblk;
    const int nout  = 16;
    const int group = (nblk + nout - 1) / nout;

    detect_mode_kernel<<<1, 256, 0, stream>>>((const unsigned int*)valid, mode_p);

    dim3 g0(nblk, NB);
    abmil_partial_kernel<<<g0, 256, 0, stream>>>(xs, valid, w1, w2, p0, mode_p,
                                                 nblk, rows_per_block);
    dim3 g1(nout, NB);
    combine_kernel<<<g1, 256, 0, stream>>>(p0, p1, nblk, group, nout);

    finalize_kernel<<<NB, 1024, 0, stream>>>(p1, nout, wf, out);
}

// Round 2
// 34.023 us; speedup vs baseline: 1.5191x; 1.5191x over previous
//
#include <hip/hip_runtime.h>
#include <hip/hip_bf16.h>
#include <math.h>

// ABMIL gated-attention pooling.
// Key insight: a = tanh(.)*sigmoid(.) is bounded in (-1,1), so softmax needs
// NO max subtraction: p = exp(a) is safe, masked rows contribute exactly 0
// (exp(-10000) underflows). All partials are purely additive, and since
// out = (z @ wf^T)/s is linear in z, each block can reduce straight to
// {pd[4], s} (32 bytes). Two kernels total.

#define NB   4
#define NN   16384
#define DD   1024
#define LL   4
#define NBLK 256            // blocks per bag
#define RPB  (NN / NBLK)    // 64 rows per block
#define RPW  (RPB / 4)      // 16 rows per wave

struct POut { float pd[LL]; float s; float pad[3]; };  // 32 B

__device__ __forceinline__ float wave_reduce(float v) {
    #pragma unroll
    for (int off = 32; off > 0; off >>= 1) v += __shfl_xor(v, off, 64);
    return v;
}

// ---------------------------------------------------------------------------
// Main: grid (NBLK, NB), 256 threads (4 waves). Each wave: ballot its 16 row
// validity bits, then process 2 rows/iter (independent chains for ILP).
// Epilogue: LDS-combine 4 waves' z, project onto wf rows, write {pd[4], s}.
// ---------------------------------------------------------------------------
__global__ __launch_bounds__(256) void abmil_main(
    const float* __restrict__ xs, const void* __restrict__ valid,
    const float* __restrict__ w1, const float* __restrict__ w2,
    const float* __restrict__ wf, POut* __restrict__ parts) {
    const int blk  = blockIdx.x;
    const int bag  = blockIdx.y;
    const int tid  = threadIdx.x;
    const int wave = tid >> 6;
    const int lane = tid & 63;

    // ---- inline dtype detection for `valid` (first 4 KB, L2-hot) ----
    // mode: 0=byte(bool), 1=int32, 2=float32
    __shared__ int nflag[2];
    if (tid == 0) { nflag[0] = 0; nflag[1] = 0; }
    __syncthreads();
    {
        const unsigned int* vw = (const unsigned int*)valid;
        int bi = 0, bf = 0;
        #pragma unroll
        for (int j = 0; j < 4; ++j) {
            const unsigned int x = vw[tid * 4 + j];
            if (x != 0u && x != 1u) bi = 1;
            if (x != 0u && x != 0x3F800000u) bf = 1;
        }
        if (bi) atomicOr(&nflag[0], 1);
        if (bf) atomicOr(&nflag[1], 1);
    }
    __syncthreads();
    const int mode = (!nflag[0]) ? 1 : ((!nflag[1]) ? 2 : 0);

    // ---- gate weights into registers (16 f32/lane each) ----
    const float4* w1v = (const float4*)w1;
    const float4* w2v = (const float4*)w2;
    float4 w1r[4], w2r[4];
    #pragma unroll
    for (int k = 0; k < 4; ++k) {
        w1r[k] = w1v[k * 64 + lane];
        w2r[k] = w2v[k * 64 + lane];
    }

    // ---- validity bitmask for this wave's 16 rows ----
    const int n0 = blk * RPB + wave * RPW;
    int flag = 0;
    if (lane < RPW) {
        const size_t idx = (size_t)bag * NN + n0 + lane;
        if (mode == 1)      flag = ((const int*)valid)[idx] != 0;
        else if (mode == 2) flag = ((const float*)valid)[idx] != 0.0f;
        else                flag = ((const unsigned char*)valid)[idx] != 0;
    }
    const unsigned long long vm = __ballot(flag);

    // ---- main loop: 2 rows per iteration ----
    float s = 0.0f;
    float4 z[4];
    #pragma unroll
    for (int k = 0; k < 4; ++k) z[k] = make_float4(0.f, 0.f, 0.f, 0.f);

    const float4* xbase = (const float4*)(xs + (size_t)bag * NN * DD);

    for (int i = 0; i < RPW; i += 2) {
        const bool v0 = (vm >> i)       & 1ull;
        const bool v1 = (vm >> (i + 1)) & 1ull;
        float4 x0[4], x1[4];
        #pragma unroll
        for (int k = 0; k < 4; ++k) {
            x0[k] = make_float4(0.f, 0.f, 0.f, 0.f);
            x1[k] = make_float4(0.f, 0.f, 0.f, 0.f);
        }
        if (v0) {
            const float4* xp = xbase + (size_t)(n0 + i) * (DD / 4);
            #pragma unroll
            for (int k = 0; k < 4; ++k) x0[k] = xp[k * 64 + lane];
        }
        if (v1) {
            const float4* xp = xbase + (size_t)(n0 + i + 1) * (DD / 4);
            #pragma unroll
            for (int k = 0; k < 4; ++k) x1[k] = xp[k * 64 + lane];
        }

        float d1a = 0.f, d2a = 0.f, d1b = 0.f, d2b = 0.f;
        #pragma unroll
        for (int k = 0; k < 4; ++k) {
            d1a += x0[k].x * w1r[k].x + x0[k].y * w1r[k].y +
                   x0[k].z * w1r[k].z + x0[k].w * w1r[k].w;
            d2a += x0[k].x * w2r[k].x + x0[k].y * w2r[k].y +
                   x0[k].z * w2r[k].z + x0[k].w * w2r[k].w;
            d1b += x1[k].x * w1r[k].x + x1[k].y * w1r[k].y +
                   x1[k].z * w1r[k].z + x1[k].w * w1r[k].w;
            d2b += x1[k].x * w2r[k].x + x1[k].y * w2r[k].y +
                   x1[k].z * w2r[k].z + x1[k].w * w2r[k].w;
        }
        // four independent reduction chains -> good ILP
        #pragma unroll
        for (int off = 32; off > 0; off >>= 1) {
            d1a += __shfl_xor(d1a, off, 64);
            d2a += __shfl_xor(d2a, off, 64);
            d1b += __shfl_xor(d1b, off, 64);
            d2b += __shfl_xor(d2b, off, 64);
        }
        const float a0 = tanhf(d1a) * (1.0f / (1.0f + __expf(-d2a)));
        const float a1 = tanhf(d1b) * (1.0f / (1.0f + __expf(-d2b)));
        const float p0 = v0 ? __expf(a0) : 0.0f;
        const float p1 = v1 ? __expf(a1) : 0.0f;
        s += p0 + p1;
        #pragma unroll
        for (int k = 0; k < 4; ++k) {
            z[k].x += p0 * x0[k].x + p1 * x1[k].x;
            z[k].y += p0 * x0[k].y + p1 * x1[k].y;
            z[k].z += p0 * x0[k].z + p1 * x1[k].z;
            z[k].w += p0 * x0[k].w + p1 * x1[k].w;
        }
    }

    // ---- block combine + wf projection ----
    __shared__ float zsh[4][DD];
    __shared__ float ssh[4];
    __shared__ float wsum[4][LL];
    #pragma unroll
    for (int k = 0; k < 4; ++k) ((float4*)zsh[wave])[k * 64 + lane] = z[k];
    if (lane == 0) ssh[wave] = s;
    __syncthreads();

    float pl[LL] = {0.f, 0.f, 0.f, 0.f};
    #pragma unroll
    for (int k = 0; k < 4; ++k) {
        const int d = tid + k * 256;
        const float zb = zsh[0][d] + zsh[1][d] + zsh[2][d] + zsh[3][d];
        #pragma unroll
        for (int l = 0; l < LL; ++l) pl[l] += zb * wf[l * DD + d];
    }
    #pragma unroll
    for (int l = 0; l < LL; ++l) pl[l] = wave_reduce(pl[l]);
    if (lane == 0) {
        #pragma unroll
        for (int l = 0; l < LL; ++l) wsum[wave][l] = pl[l];
    }
    __syncthreads();

    POut* po = &parts[(size_t)bag * NBLK + blk];
    if (tid < LL)
        po->pd[tid] = wsum[0][tid] + wsum[1][tid] + wsum[2][tid] + wsum[3][tid];
    if (tid == LL)
        po->s = ssh[0] + ssh[1] + ssh[2] + ssh[3];
}

// ---------------------------------------------------------------------------
// Finish: 1 block, 256 threads. Wave w owns bag w; 64 lanes sum 256 POuts,
// shuffle-reduce, divide, store 16 floats.
// ---------------------------------------------------------------------------
__global__ __launch_bounds__(256) void abmil_finish(
    const POut* __restrict__ parts, float* __restrict__ out) {
    const int bag  = threadIdx.x >> 6;
    const int lane = threadIdx.x & 63;

    float pd[LL] = {0.f, 0.f, 0.f, 0.f};
    float s = 0.0f;
    #pragma unroll
    for (int j = 0; j < NBLK / 64; ++j) {
        const POut* p = &parts[(size_t)bag * NBLK + j * 64 + lane];
        #pragma unroll
        for (int l = 0; l < LL; ++l) pd[l] += p->pd[l];
        s += p->s;
    }
    #pragma unroll
    for (int l = 0; l < LL; ++l) pd[l] = wave_reduce(pd[l]);
    s = wave_reduce(s);
    if (lane == 0) {
        #pragma unroll
        for (int l = 0; l < LL; ++l) out[bag * LL + l] = pd[l] / s;
    }
}

// ---------------------------------------------------------------------------
extern "C" void kernel_launch(void* const* d_in, const int* in_sizes, int n_in,
                              void* d_out, int out_size, void* d_ws, size_t ws_size,
                              hipStream_t stream) {
    const float* xs    = (const float*)d_in[0];
    const void*  valid = d_in[1];
    const float* w1    = (const float*)d_in[2];
    const float* w2    = (const float*)d_in[3];
    const float* wf    = (const float*)d_in[4];
    float* out = (float*)d_out;

    POut* parts = (POut*)d_ws;   // NB*NBLK*32 B = 32 KB << ws_size

    dim3 g0(NBLK, NB);
    abmil_main<<<g0, 256, 0, stream>>>(xs, valid, w1, w2, wf, parts);
    abmil_finish<<<1, 256, 0, stream>>>(parts, out);
}